// Round 1
// baseline (6202.267 us; speedup 1.0000x reference)
//
#include <hip/hip_runtime.h>

// SiameseGNN: 2-layer GCN on two graphs (N=100000, d=64, E=1600000 each),
// mean-pool + FC -> two 64-vectors (out_size = 128 fp32).
//
// Round 1: correctness-first baseline.
//   - degree via fp32 atomics (exact: counts < 2^24)
//   - per-edge norm precomputed (reused across both layers)
//   - GEMM 64x64 weights staged in LDS, 4 rows/block
//   - aggregation: self-loop init + atomic scatter (16 threads/edge, float4 gather)
//   - column-sum reduction + tiny FC epilogue

#define TPB 256

__global__ void k_fill1(float* __restrict__ p, int n) {
    int i = blockIdx.x * blockDim.x + threadIdx.x;
    if (i < n) p[i] = 1.0f;
}

__global__ void k_count(const int* __restrict__ dst, float* __restrict__ deg, int E) {
    int e = blockIdx.x * blockDim.x + threadIdx.x;
    if (e < E) atomicAdd(&deg[dst[e]], 1.0f);
}

__global__ void k_rsqrt(float* __restrict__ p, int n) {
    int i = blockIdx.x * blockDim.x + threadIdx.x;
    if (i < n) p[i] = rsqrtf(p[i]);   // deg >= 1 always (self-loop), no zero guard needed
}

__global__ void k_norm(const int* __restrict__ src, const int* __restrict__ dst,
                       const float* __restrict__ dinv, float* __restrict__ norm, int E) {
    int e = blockIdx.x * blockDim.x + threadIdx.x;
    if (e < E) norm[e] = dinv[src[e]] * dinv[dst[e]];
}

// H[row, c] = sum_k X[row, k] * W[k, c]   (X: n x 64, W: 64 x 64 row-major)
// block = 256 threads = 4 rows x 64 cols; W staged in LDS (16 KiB).
__global__ __launch_bounds__(256) void k_gemm64(const float* __restrict__ X,
                                                const float* __restrict__ W,
                                                float* __restrict__ H, int n) {
    __shared__ float Ws[64 * 64];
    __shared__ float Xs[4 * 64];
    int tid = threadIdx.x;
    for (int i = tid; i < 64 * 64; i += 256) Ws[i] = W[i];
    int row0 = blockIdx.x * 4;
    int idx = row0 * 64 + tid;          // 256 consecutive floats = 4 rows
    Xs[tid] = (idx < n * 64) ? X[idx] : 0.0f;
    __syncthreads();
    int r = tid >> 6, c = tid & 63;
    int row = row0 + r;
    if (row < n) {
        float acc = 0.0f;
#pragma unroll
        for (int k = 0; k < 64; ++k) acc += Xs[r * 64 + k] * Ws[k * 64 + c];
        H[row * 64 + c] = acc;
    }
}

// A[n, f] = H[n, f] * dinv[n]^2   (self-loop term; also zero-initializes A)
__global__ void k_selfloop(const float* __restrict__ H, const float* __restrict__ dinv,
                           float* __restrict__ A, int total) {
    int i = blockIdx.x * blockDim.x + threadIdx.x;
    if (i < total) {
        float d = dinv[i >> 6];
        A[i] = H[i] * d * d;
    }
}

// For each edge e: A[dst, :] += H[src, :] * norm[e].  16 threads/edge, float4 each.
__global__ void k_scatter(const int* __restrict__ src, const int* __restrict__ dst,
                          const float* __restrict__ norm, const float* __restrict__ H,
                          float* __restrict__ A, int E) {
    int t = blockIdx.x * blockDim.x + threadIdx.x;
    int e = t >> 4;
    if (e >= E) return;
    int q = t & 15;
    float nrm = norm[e];
    int s = src[e], d = dst[e];
    float4 hv = ((const float4*)H)[s * 16 + q];
    float* out = A + d * 64 + q * 4;
    atomicAdd(out + 0, hv.x * nrm);
    atomicAdd(out + 1, hv.y * nrm);
    atomicAdd(out + 2, hv.z * nrm);
    atomicAdd(out + 3, hv.w * nrm);
}

__global__ void k_bias_relu(float* __restrict__ A, const float* __restrict__ b, int total) {
    int i = blockIdx.x * blockDim.x + threadIdx.x;
    if (i < total) {
        float v = A[i] + b[i & 63];
        A[i] = v > 0.0f ? v : 0.0f;
    }
}

__global__ void k_zero64(float* __restrict__ S) {
    if (threadIdx.x < 64) S[threadIdx.x] = 0.0f;
}

// Column sums of A (n x 64) into S[64].  One wave per block, grid-stride rows.
__global__ void k_colsum(const float* __restrict__ A, float* __restrict__ S, int n) {
    int f = threadIdx.x;  // 0..63
    float acc = 0.0f;
    for (int r = blockIdx.x; r < n; r += gridDim.x) acc += A[r * 64 + f];
    atomicAdd(&S[f], acc);
}

// out[j] = fc_b[j] + (1/n) * sum_k S[k] * fc_w[j, k]
__global__ void k_fc(const float* __restrict__ S, const float* __restrict__ fcw,
                     const float* __restrict__ fcb, float* __restrict__ out, int n) {
    int j = threadIdx.x;  // 0..63
    float inv = 1.0f / (float)n;
    float acc = fcb[j];
#pragma unroll
    for (int k = 0; k < 64; ++k) acc += (S[k] * inv) * fcw[j * 64 + k];
    out[j] = acc;
}

extern "C" void kernel_launch(void* const* d_in, const int* in_sizes, int n_in,
                              void* d_out, int out_size, void* d_ws, size_t ws_size,
                              hipStream_t stream) {
    const float* x[2]   = {(const float*)d_in[0], (const float*)d_in[1]};
    const int*   ei[2]  = {(const int*)d_in[2], (const int*)d_in[3]};
    const float* W1  = (const float*)d_in[4];
    const float* b1  = (const float*)d_in[5];
    const float* W2  = (const float*)d_in[6];
    const float* b2  = (const float*)d_in[7];
    const float* fcw = (const float*)d_in[8];
    const float* fcb = (const float*)d_in[9];
    float* out = (float*)d_out;

    const int N = in_sizes[0] / 64;
    const int E = in_sizes[2] / 2;
    const int NF = N * 64;

    // workspace layout (floats)
    float* H    = (float*)d_ws;            // N*64
    float* A    = H + (size_t)NF;          // N*64
    float* dinv = A + (size_t)NF;          // N
    float* nrm  = dinv + (size_t)N;        // E
    float* S    = nrm + (size_t)E;         // 64

    const int gN   = (N + TPB - 1) / TPB;
    const int gE   = (E + TPB - 1) / TPB;
    const int gNF  = (NF + TPB - 1) / TPB;
    const int gSc  = (E * 16 + TPB - 1) / TPB;
    const int gGm  = (N + 3) / 4;

    for (int g = 0; g < 2; ++g) {
        const int* esrc = ei[g];
        const int* edst = ei[g] + E;

        // normalization
        k_fill1<<<gN, TPB, 0, stream>>>(dinv, N);
        k_count<<<gE, TPB, 0, stream>>>(edst, dinv, E);
        k_rsqrt<<<gN, TPB, 0, stream>>>(dinv, N);
        k_norm<<<gE, TPB, 0, stream>>>(esrc, edst, dinv, nrm, E);

        // layer 1
        k_gemm64<<<gGm, TPB, 0, stream>>>(x[g], W1, H, N);
        k_selfloop<<<gNF, TPB, 0, stream>>>(H, dinv, A, NF);
        k_scatter<<<gSc, TPB, 0, stream>>>(esrc, edst, nrm, H, A, E);
        k_bias_relu<<<gNF, TPB, 0, stream>>>(A, b1, NF);

        // layer 2
        k_gemm64<<<gGm, TPB, 0, stream>>>(A, W2, H, N);
        k_selfloop<<<gNF, TPB, 0, stream>>>(H, dinv, A, NF);
        k_scatter<<<gSc, TPB, 0, stream>>>(esrc, edst, nrm, H, A, E);
        k_bias_relu<<<gNF, TPB, 0, stream>>>(A, b2, NF);

        // mean-pool + FC
        k_zero64<<<1, 64, 0, stream>>>(S);
        k_colsum<<<256, 64, 0, stream>>>(A, S, N);
        k_fc<<<1, 64, 0, stream>>>(S, fcw, fcb, out + g * 64, N);
    }
}

// Round 2
// 1167.933 us; speedup vs baseline: 5.3105x; 5.3105x over previous
//
#include <hip/hip_runtime.h>

// SiameseGNN round 2: replace atomic scatter-add aggregation with CSR-by-dst
// gather aggregation (zero float atomics in the hot path).
//
// Per graph:
//   1. cnt[d]       = #incoming edges (int atomics, 1.6M)
//   2. dinv[d]      = rsqrt(cnt[d] + 1)            (self-loop included)
//   3. row_ptr      = exclusive scan of cnt (3-kernel hierarchical scan)
//   4. csr_src      = edge sources bucketed by dst (int atomics on cursor)
//   5. Hs = (X @ W) * dinv[row]                    (GEMM epilogue scale)
//   6. A[d,f] = relu(b[f] + dinv[d]*(Hs[d,f] + sum_{s in in(d)} Hs[s,f]))
//   7. mean-pool + FC
//
// Round 1 evidence: 4x k_scatter = 5405/6202 us, WRITE_SIZE 1.6 GB/dispatch
// (atomics forced past L2), VALUBusy 1% -> atomic-RMW bound. This removes them.

#define TPB 256

__global__ void k_zero_int(int* __restrict__ p, int n) {
    int i = blockIdx.x * blockDim.x + threadIdx.x;
    if (i < n) p[i] = 0;
}

__global__ void k_count_int(const int* __restrict__ dst, int* __restrict__ cnt, int E) {
    int e = blockIdx.x * blockDim.x + threadIdx.x;
    if (e < E) atomicAdd(&cnt[dst[e]], 1);
}

__global__ void k_dinv(const int* __restrict__ cnt, float* __restrict__ dinv, int n) {
    int i = blockIdx.x * blockDim.x + threadIdx.x;
    if (i < n) dinv[i] = rsqrtf((float)cnt[i] + 1.0f);
}

// --- hierarchical exclusive scan of cnt[0..n) -> row_ptr[0..n) ---
// scan1: per-256-block exclusive scan, block totals to bsum
__global__ __launch_bounds__(256) void k_scan1(const int* __restrict__ cnt,
                                               int* __restrict__ row_ptr,
                                               int* __restrict__ bsum, int n) {
    __shared__ int s[256];
    int tid = threadIdx.x;
    int i = blockIdx.x * 256 + tid;
    int v = (i < n) ? cnt[i] : 0;
    s[tid] = v;
    __syncthreads();
#pragma unroll
    for (int off = 1; off < 256; off <<= 1) {
        int t = (tid >= off) ? s[tid - off] : 0;
        __syncthreads();
        s[tid] += t;
        __syncthreads();
    }
    if (i < n) row_ptr[i] = s[tid] - v;          // exclusive
    if (tid == 255) bsum[blockIdx.x] = s[255];   // block total
}

// scan2: single block, exclusive scan of bsum[0..B), B <= 1024
__global__ __launch_bounds__(1024) void k_scan2(int* __restrict__ bsum, int B) {
    __shared__ int s[1024];
    int tid = threadIdx.x;
    int v = (tid < B) ? bsum[tid] : 0;
    s[tid] = v;
    __syncthreads();
#pragma unroll
    for (int off = 1; off < 1024; off <<= 1) {
        int t = (tid >= off) ? s[tid - off] : 0;
        __syncthreads();
        s[tid] += t;
        __syncthreads();
    }
    if (tid < B) bsum[tid] = s[tid] - v;
}

// scan3: add block offsets; also initialize cursor (reuses cnt) and row_ptr[n]=E
__global__ __launch_bounds__(256) void k_scan3(int* __restrict__ row_ptr,
                                               const int* __restrict__ bsum,
                                               int* __restrict__ cursor, int n, int E) {
    int i = blockIdx.x * 256 + threadIdx.x;
    if (i < n) {
        int r = row_ptr[i] + bsum[blockIdx.x];
        row_ptr[i] = r;
        cursor[i] = r;
    }
    if (i == 0) row_ptr[n] = E;
}

__global__ void k_fill_csr(const int* __restrict__ src, const int* __restrict__ dst,
                           int* __restrict__ cursor, int* __restrict__ csr_src, int E) {
    int e = blockIdx.x * blockDim.x + threadIdx.x;
    if (e < E) {
        int slot = atomicAdd(&cursor[dst[e]], 1);
        csr_src[slot] = src[e];
    }
}

// Hs[row, c] = dinv[row] * sum_k X[row, k] * W[k, c]
__global__ __launch_bounds__(256) void k_gemm64(const float* __restrict__ X,
                                                const float* __restrict__ W,
                                                const float* __restrict__ dinv,
                                                float* __restrict__ Hs, int n) {
    __shared__ float Ws[64 * 64];
    __shared__ float Xs[4 * 64];
    int tid = threadIdx.x;
    for (int i = tid; i < 64 * 64; i += 256) Ws[i] = W[i];
    int row0 = blockIdx.x * 4;
    int idx = row0 * 64 + tid;
    Xs[tid] = (idx < n * 64) ? X[idx] : 0.0f;
    __syncthreads();
    int r = tid >> 6, c = tid & 63;
    int row = row0 + r;
    if (row < n) {
        float acc = 0.0f;
#pragma unroll
        for (int k = 0; k < 64; ++k) acc += Xs[r * 64 + k] * Ws[k * 64 + c];
        Hs[row * 64 + c] = acc * dinv[row];
    }
}

// A[d, f] = relu(b[f] + dinv[d] * (Hs[d, f] + sum_{s in in(d)} Hs[s, f]))
// one wave per node, lane = feature; coalesced 256B row gathers, no atomics.
__global__ __launch_bounds__(256) void k_aggregate(const float* __restrict__ Hs,
                                                   const int* __restrict__ csr_src,
                                                   const int* __restrict__ row_ptr,
                                                   const float* __restrict__ dinv,
                                                   const float* __restrict__ bias,
                                                   float* __restrict__ A, int n) {
    int node = blockIdx.x * 4 + (threadIdx.x >> 6);
    int lane = threadIdx.x & 63;
    if (node >= n) return;
    int beg = __builtin_amdgcn_readfirstlane(row_ptr[node]);
    int end = __builtin_amdgcn_readfirstlane(row_ptr[node + 1]);
    float acc = Hs[node * 64 + lane];   // self-loop term (Hs already dinv-scaled)
    int j = beg;
    for (; j + 1 < end; j += 2) {       // unroll 2 for load ILP
        int s0 = __builtin_amdgcn_readfirstlane(csr_src[j]);
        int s1 = __builtin_amdgcn_readfirstlane(csr_src[j + 1]);
        float a0 = Hs[s0 * 64 + lane];
        float a1 = Hs[s1 * 64 + lane];
        acc += a0 + a1;
    }
    if (j < end) {
        int s0 = __builtin_amdgcn_readfirstlane(csr_src[j]);
        acc += Hs[s0 * 64 + lane];
    }
    float v = bias[lane] + dinv[node] * acc;
    A[node * 64 + lane] = fmaxf(v, 0.0f);
}

__global__ void k_zero64(float* __restrict__ S) {
    if (threadIdx.x < 64) S[threadIdx.x] = 0.0f;
}

__global__ void k_colsum(const float* __restrict__ A, float* __restrict__ S, int n) {
    int f = threadIdx.x;  // 0..63
    float acc = 0.0f;
    for (int r = blockIdx.x; r < n; r += gridDim.x) acc += A[r * 64 + f];
    atomicAdd(&S[f], acc);
}

__global__ void k_fc(const float* __restrict__ S, const float* __restrict__ fcw,
                     const float* __restrict__ fcb, float* __restrict__ out, int n) {
    int j = threadIdx.x;  // 0..63
    float inv = 1.0f / (float)n;
    float acc = fcb[j];
#pragma unroll
    for (int k = 0; k < 64; ++k) acc += (S[k] * inv) * fcw[j * 64 + k];
    out[j] = acc;
}

extern "C" void kernel_launch(void* const* d_in, const int* in_sizes, int n_in,
                              void* d_out, int out_size, void* d_ws, size_t ws_size,
                              hipStream_t stream) {
    const float* x[2]  = {(const float*)d_in[0], (const float*)d_in[1]};
    const int*   ei[2] = {(const int*)d_in[2], (const int*)d_in[3]};
    const float* W1  = (const float*)d_in[4];
    const float* b1  = (const float*)d_in[5];
    const float* W2  = (const float*)d_in[6];
    const float* b2  = (const float*)d_in[7];
    const float* fcw = (const float*)d_in[8];
    const float* fcb = (const float*)d_in[9];
    float* out = (float*)d_out;

    const int N  = in_sizes[0] / 64;
    const int E  = in_sizes[2] / 2;
    const int NF = N * 64;

    // workspace layout (4-byte elems), ~59 MB total
    float* H       = (float*)d_ws;                 // NF
    float* A       = H + (size_t)NF;               // NF
    float* dinv    = A + (size_t)NF;               // N
    int*   cnt     = (int*)(dinv + (size_t)N);     // N   (reused as cursor)
    int*   row_ptr = cnt + (size_t)N;              // N+1
    int*   bsum    = row_ptr + (size_t)(N + 1);    // 1024
    float* S       = (float*)(bsum + 1024);        // 64
    int*   csr_src = (int*)(S + 64);               // E

    const int gN  = (N + TPB - 1) / TPB;
    const int gE  = (E + TPB - 1) / TPB;
    const int gGm = (N + 3) / 4;
    const int B   = (N + 255) / 256;               // scan blocks (<=1024)

    for (int g = 0; g < 2; ++g) {
        const int* esrc = ei[g];
        const int* edst = ei[g] + E;

        // CSR build + normalization
        k_zero_int<<<gN, TPB, 0, stream>>>(cnt, N);
        k_count_int<<<gE, TPB, 0, stream>>>(edst, cnt, E);
        k_dinv<<<gN, TPB, 0, stream>>>(cnt, dinv, N);
        k_scan1<<<B, 256, 0, stream>>>(cnt, row_ptr, bsum, N);
        k_scan2<<<1, 1024, 0, stream>>>(bsum, B);
        k_scan3<<<B, 256, 0, stream>>>(row_ptr, bsum, cnt, N, E);
        k_fill_csr<<<gE, TPB, 0, stream>>>(esrc, edst, cnt, csr_src, E);

        // layer 1
        k_gemm64<<<gGm, TPB, 0, stream>>>(x[g], W1, dinv, H, N);
        k_aggregate<<<gGm, TPB, 0, stream>>>(H, csr_src, row_ptr, dinv, b1, A, N);

        // layer 2
        k_gemm64<<<gGm, TPB, 0, stream>>>(A, W2, dinv, H, N);
        k_aggregate<<<gGm, TPB, 0, stream>>>(H, csr_src, row_ptr, dinv, b2, A, N);

        // mean-pool + FC
        k_zero64<<<1, 64, 0, stream>>>(S);
        k_colsum<<<256, 64, 0, stream>>>(A, S, N);
        k_fc<<<1, 64, 0, stream>>>(S, fcw, fcb, out + g * 64, N);
    }
}

// Round 3
// 952.301 us; speedup vs baseline: 6.5129x; 1.2264x over previous
//
#include <hip/hip_runtime.h>

// SiameseGNN round 3: bf16 feature gathers + fusions.
//   - Hs (post-GEMM, dinv-scaled features) stored as bf16: halves the
//     aggregate's gather traffic (dominant remaining cost, L3-bound).
//     Error budget: bf16 RNE ~2e-3 rel on ~0.24-magnitude values, sqrt-
//     cancellation over ~17-edge sums and 100K-node mean-pool -> ~1e-5
//     final error vs 2.7e-3 threshold.
//   - dinv computation folded into scan1 (reads cnt anyway).
//   - layer-2 aggregate never materializes A: block-reduces 4 relu'd rows
//     in LDS, writes 6.4 MB of column partials P instead of 25.6 MB A.
//   - aggregate inner loop unrolled x4 for load ILP.
// k_fill_csr (127 us, partial-line scatter bound) deliberately untouched:
// candidate for LDS-staged binning next round if it tops the profile.

#define TPB 256

__device__ __forceinline__ float bf2f(unsigned short u) {
    union { unsigned int i; float f; } c; c.i = ((unsigned int)u) << 16; return c.f;
}
__device__ __forceinline__ unsigned short f2bf(float x) {
    union { float f; unsigned int i; } c; c.f = x;
    unsigned int r = c.i + 0x7FFFu + ((c.i >> 16) & 1u);   // round-to-nearest-even
    return (unsigned short)(r >> 16);
}

__global__ void k_zero_int(int* __restrict__ p, int n) {
    int i = blockIdx.x * blockDim.x + threadIdx.x;
    if (i < n) p[i] = 0;
}

__global__ void k_count_int(const int* __restrict__ dst, int* __restrict__ cnt, int E) {
    int e = blockIdx.x * blockDim.x + threadIdx.x;
    if (e < E) atomicAdd(&cnt[dst[e]], 1);
}

// per-256-block exclusive scan of cnt -> row_ptr, block totals -> bsum,
// fused: dinv[i] = rsqrt(cnt[i] + 1)
__global__ __launch_bounds__(256) void k_scan1(const int* __restrict__ cnt,
                                               int* __restrict__ row_ptr,
                                               int* __restrict__ bsum,
                                               float* __restrict__ dinv, int n) {
    __shared__ int s[256];
    int tid = threadIdx.x;
    int i = blockIdx.x * 256 + tid;
    int v = (i < n) ? cnt[i] : 0;
    if (i < n) dinv[i] = rsqrtf((float)v + 1.0f);
    s[tid] = v;
    __syncthreads();
#pragma unroll
    for (int off = 1; off < 256; off <<= 1) {
        int t = (tid >= off) ? s[tid - off] : 0;
        __syncthreads();
        s[tid] += t;
        __syncthreads();
    }
    if (i < n) row_ptr[i] = s[tid] - v;
    if (tid == 255) bsum[blockIdx.x] = s[255];
}

__global__ __launch_bounds__(1024) void k_scan2(int* __restrict__ bsum, int B) {
    __shared__ int s[1024];
    int tid = threadIdx.x;
    int v = (tid < B) ? bsum[tid] : 0;
    s[tid] = v;
    __syncthreads();
#pragma unroll
    for (int off = 1; off < 1024; off <<= 1) {
        int t = (tid >= off) ? s[tid - off] : 0;
        __syncthreads();
        s[tid] += t;
        __syncthreads();
    }
    if (tid < B) bsum[tid] = s[tid] - v;
}

__global__ __launch_bounds__(256) void k_scan3(int* __restrict__ row_ptr,
                                               const int* __restrict__ bsum,
                                               int* __restrict__ cursor, int n, int E) {
    int i = blockIdx.x * 256 + threadIdx.x;
    if (i < n) {
        int r = row_ptr[i] + bsum[blockIdx.x];
        row_ptr[i] = r;
        cursor[i] = r;
    }
    if (i == 0) row_ptr[n] = E;
}

__global__ void k_fill_csr(const int* __restrict__ src, const int* __restrict__ dst,
                           int* __restrict__ cursor, int* __restrict__ csr_src, int E) {
    int e = blockIdx.x * blockDim.x + threadIdx.x;
    if (e < E) {
        int slot = atomicAdd(&cursor[dst[e]], 1);
        csr_src[slot] = src[e];
    }
}

// Hs[row, c] = bf16( dinv[row] * sum_k X[row, k] * W[k, c] )
__global__ __launch_bounds__(256) void k_gemm64(const float* __restrict__ X,
                                                const float* __restrict__ W,
                                                const float* __restrict__ dinv,
                                                unsigned short* __restrict__ Hs, int n) {
    __shared__ float Ws[64 * 64];
    __shared__ float Xs[4 * 64];
    int tid = threadIdx.x;
    for (int i = tid; i < 64 * 64; i += 256) Ws[i] = W[i];
    int row0 = blockIdx.x * 4;
    int idx = row0 * 64 + tid;
    Xs[tid] = (idx < n * 64) ? X[idx] : 0.0f;
    __syncthreads();
    int r = tid >> 6, c = tid & 63;
    int row = row0 + r;
    if (row < n) {
        float acc = 0.0f;
#pragma unroll
        for (int k = 0; k < 64; ++k) acc += Xs[r * 64 + k] * Ws[k * 64 + c];
        Hs[row * 64 + c] = f2bf(acc * dinv[row]);
    }
}

__device__ __forceinline__ float agg_node(const unsigned short* __restrict__ Hs,
                                          const int* __restrict__ csr_src,
                                          const int* __restrict__ row_ptr,
                                          int node, int lane) {
    int beg = __builtin_amdgcn_readfirstlane(row_ptr[node]);
    int end = __builtin_amdgcn_readfirstlane(row_ptr[node + 1]);
    float acc = bf2f(Hs[node * 64 + lane]);   // self-loop (Hs already dinv-scaled)
    int j = beg;
    for (; j + 3 < end; j += 4) {
        int s0 = __builtin_amdgcn_readfirstlane(csr_src[j]);
        int s1 = __builtin_amdgcn_readfirstlane(csr_src[j + 1]);
        int s2 = __builtin_amdgcn_readfirstlane(csr_src[j + 2]);
        int s3 = __builtin_amdgcn_readfirstlane(csr_src[j + 3]);
        float a0 = bf2f(Hs[s0 * 64 + lane]);
        float a1 = bf2f(Hs[s1 * 64 + lane]);
        float a2 = bf2f(Hs[s2 * 64 + lane]);
        float a3 = bf2f(Hs[s3 * 64 + lane]);
        acc += (a0 + a1) + (a2 + a3);
    }
    for (; j < end; ++j) {
        int s0 = __builtin_amdgcn_readfirstlane(csr_src[j]);
        acc += bf2f(Hs[s0 * 64 + lane]);
    }
    return acc;
}

// layer-1: A[d, f] = relu(b[f] + dinv[d] * agg)   (fp32, feeds gemm2)
__global__ __launch_bounds__(256) void k_aggregate1(const unsigned short* __restrict__ Hs,
                                                    const int* __restrict__ csr_src,
                                                    const int* __restrict__ row_ptr,
                                                    const float* __restrict__ dinv,
                                                    const float* __restrict__ bias,
                                                    float* __restrict__ A, int n) {
    int node = blockIdx.x * 4 + (threadIdx.x >> 6);
    int lane = threadIdx.x & 63;
    if (node >= n) return;
    float acc = agg_node(Hs, csr_src, row_ptr, node, lane);
    float v = bias[lane] + dinv[node] * acc;
    A[node * 64 + lane] = fmaxf(v, 0.0f);
}

// layer-2: never materialize A; block-reduce 4 relu'd rows -> P[block, f]
__global__ __launch_bounds__(256) void k_aggregate2(const unsigned short* __restrict__ Hs,
                                                    const int* __restrict__ csr_src,
                                                    const int* __restrict__ row_ptr,
                                                    const float* __restrict__ dinv,
                                                    const float* __restrict__ bias,
                                                    float* __restrict__ P, int n) {
    __shared__ float red[256];
    int node = blockIdx.x * 4 + (threadIdx.x >> 6);
    int lane = threadIdx.x & 63;
    float val = 0.0f;
    if (node < n) {
        float acc = agg_node(Hs, csr_src, row_ptr, node, lane);
        val = fmaxf(bias[lane] + dinv[node] * acc, 0.0f);
    }
    red[threadIdx.x] = val;
    __syncthreads();
    if (threadIdx.x < 64) {
        float s = red[threadIdx.x] + red[64 + threadIdx.x] +
                  red[128 + threadIdx.x] + red[192 + threadIdx.x];
        P[blockIdx.x * 64 + threadIdx.x] = s;
    }
}

__global__ void k_zero64(float* __restrict__ S) {
    if (threadIdx.x < 64) S[threadIdx.x] = 0.0f;
}

__global__ void k_colsum(const float* __restrict__ P, float* __restrict__ S, int rows) {
    int f = threadIdx.x;  // 0..63
    float acc = 0.0f;
    for (int r = blockIdx.x; r < rows; r += gridDim.x) acc += P[r * 64 + f];
    atomicAdd(&S[f], acc);
}

__global__ void k_fc(const float* __restrict__ S, const float* __restrict__ fcw,
                     const float* __restrict__ fcb, float* __restrict__ out, int n) {
    int j = threadIdx.x;  // 0..63
    float inv = 1.0f / (float)n;
    float acc = fcb[j];
#pragma unroll
    for (int k = 0; k < 64; ++k) acc += (S[k] * inv) * fcw[j * 64 + k];
    out[j] = acc;
}

extern "C" void kernel_launch(void* const* d_in, const int* in_sizes, int n_in,
                              void* d_out, int out_size, void* d_ws, size_t ws_size,
                              hipStream_t stream) {
    const float* x[2]  = {(const float*)d_in[0], (const float*)d_in[1]};
    const int*   ei[2] = {(const int*)d_in[2], (const int*)d_in[3]};
    const float* W1  = (const float*)d_in[4];
    const float* b1  = (const float*)d_in[5];
    const float* W2  = (const float*)d_in[6];
    const float* b2  = (const float*)d_in[7];
    const float* fcw = (const float*)d_in[8];
    const float* fcb = (const float*)d_in[9];
    float* out = (float*)d_out;

    const int N  = in_sizes[0] / 64;
    const int E  = in_sizes[2] / 2;
    const int NF = N * 64;
    const int gGm = (N + 3) / 4;      // gemm/aggregate blocks (4 nodes each)

    // workspace layout (bytes): ~52 MB
    unsigned short* Hs = (unsigned short*)d_ws;          // NF bf16 (12.8 MB)
    float* A       = (float*)(Hs + (size_t)NF);          // NF fp32 (25.6 MB)
    float* P       = A + (size_t)NF;                     // gGm*64 (6.4 MB)
    float* dinv    = P + (size_t)gGm * 64;               // N
    int*   cnt     = (int*)(dinv + (size_t)N);           // N (reused as cursor)
    int*   row_ptr = cnt + (size_t)N;                    // N+1
    int*   bsum    = row_ptr + (size_t)(N + 1);          // 1024
    float* S       = (float*)(bsum + 1024);              // 64
    int*   csr_src = (int*)(S + 64);                     // E (6.4 MB)

    const int gN = (N + TPB - 1) / TPB;
    const int gE = (E + TPB - 1) / TPB;
    const int B  = (N + 255) / 256;   // scan blocks (<=1024)

    for (int g = 0; g < 2; ++g) {
        const int* esrc = ei[g];
        const int* edst = ei[g] + E;

        // CSR build + normalization
        k_zero_int<<<gN, TPB, 0, stream>>>(cnt, N);
        k_count_int<<<gE, TPB, 0, stream>>>(edst, cnt, E);
        k_scan1<<<B, 256, 0, stream>>>(cnt, row_ptr, bsum, dinv, N);
        k_scan2<<<1, 1024, 0, stream>>>(bsum, B);
        k_scan3<<<B, 256, 0, stream>>>(row_ptr, bsum, cnt, N, E);
        k_fill_csr<<<gE, TPB, 0, stream>>>(esrc, edst, cnt, csr_src, E);

        // layer 1
        k_gemm64<<<gGm, TPB, 0, stream>>>(x[g], W1, dinv, Hs, N);
        k_aggregate1<<<gGm, TPB, 0, stream>>>(Hs, csr_src, row_ptr, dinv, b1, A, N);

        // layer 2 (A never re-materialized; column partials P instead)
        k_gemm64<<<gGm, TPB, 0, stream>>>(A, W2, dinv, Hs, N);
        k_aggregate2<<<gGm, TPB, 0, stream>>>(Hs, csr_src, row_ptr, dinv, b2, P, N);

        // mean-pool + FC
        k_zero64<<<1, 64, 0, stream>>>(S);
        k_colsum<<<256, 64, 0, stream>>>(P, S, gGm);
        k_fc<<<1, 64, 0, stream>>>(S, fcw, fcb, out + g * 64, N);
    }
}